// Round 11
// baseline (71.342 us; speedup 1.0000x reference)
//
#include <hip/hip_runtime.h>
#include <math.h>

#define FEAT 64

typedef float    f32x4 __attribute__((ext_vector_type(4)));
typedef int      i32x4 __attribute__((ext_vector_type(4)));
typedef _Float16 f16x4 __attribute__((ext_vector_type(4)));

// dequant-accumulate one packed word (4 biased-uint8 feats) into acc.
// (float)(u & 255) folds to v_cvt_f32_ubyte{0..3}.
__device__ __forceinline__ void dq_acc(int p, float wk, f32x4& acc) {
    unsigned up = (unsigned)p;
    acc.x = fmaf(wk, (float)(up & 255u),         acc.x);
    acc.y = fmaf(wk, (float)((up >> 8) & 255u),  acc.y);
    acc.z = fmaf(wk, (float)((up >> 16) & 255u), acc.z);
    acc.w = fmaf(wk, (float)(up >> 24),          acc.w);
}

// ---------- pre-pass: per-row biased-uint8 quantization, 4-deep MLP ----------
// Each wave: 16 rows as 4 independent {load,reduce,pack,store} chains, loads
// issued back-to-back. Plain stores to d_ws (R5 lesson: no nt stores to
// device-consumed buffers).
__global__ __launch_bounds__(256) void quant_kernel(
    const float* __restrict__ values,
    int* __restrict__ vq,          // 16 packed dwords per row (64B)
    float* __restrict__ scale,
    int num_rows)
{
    const int lane = threadIdx.x & 63;
    const int g    = lane >> 4;
    const int f4   = lane & 15;
    const int wave = blockIdx.x * 4 + (threadIdx.x >> 6);
    const int rbase = wave * 16 + g;      // rows rbase + 4*i, i=0..3

    f32x4 v[4];
    #pragma unroll
    for (int i = 0; i < 4; ++i) {
        const int row = rbase + i * 4;
        v[i] = (f32x4){0.0f, 0.0f, 0.0f, 0.0f};
        if (row < num_rows)
            v[i] = __builtin_nontemporal_load(
                       (const f32x4*)(values + (long long)row * FEAT) + f4);
    }

    #pragma unroll
    for (int i = 0; i < 4; ++i) {
        const int row = rbase + i * 4;
        float a = fmaxf(fmaxf(fabsf(v[i].x), fabsf(v[i].y)),
                        fmaxf(fabsf(v[i].z), fabsf(v[i].w)));
        a = fmaxf(a, __shfl_xor(a, 1));
        a = fmaxf(a, __shfl_xor(a, 2));
        a = fmaxf(a, __shfl_xor(a, 4));
        a = fmaxf(a, __shfl_xor(a, 8));
        if (row < num_rows) {
            const float inv = (a > 0.0f) ? 127.0f / a : 0.0f;
            int q0 = (int)rintf(v[i].x * inv) + 128;
            int q1 = (int)rintf(v[i].y * inv) + 128;
            int q2 = (int)rintf(v[i].z * inv) + 128;
            int q3 = (int)rintf(v[i].w * inv) + 128;
            vq[((unsigned)row << 4) + f4] = q0 | (q1 << 8) | (q2 << 16) | (q3 << 24);
            if (f4 == 0) scale[row] = a * (1.0f / 127.0f);
        }
    }
}

// generic per-node fallback (any degree, either index width, fp32 values)
__device__ __noinline__ void node_generic(
    const void* row_ptr_v, const void* col_idx_v, const float* scores,
    const float* values, float* out, int node, int lane, bool idx64)
{
    const int* rp32 = (const int*)row_ptr_v;
    long long start, end;
    if (idx64) {
        const long long* rp = (const long long*)row_ptr_v;
        start = rp[node]; end = rp[node + 1];
    } else {
        start = (long long)rp32[node]; end = (long long)rp32[node + 1];
    }
    float m = -INFINITY;
    for (long long e = start; e < end; ++e) m = fmaxf(m, scores[e]);
    float sum = 0.0f;
    for (long long e = start; e < end; ++e) sum += __expf(scores[e] - m);
    const float invs = (sum > 0.0f) ? 1.0f / sum : 0.0f;
    float acc = 0.0f;
    for (long long e = start; e < end; ++e) {
        long long c = idx64 ? ((const long long*)col_idx_v)[e]
                            : (long long)((const int*)col_idx_v)[e];
        acc += __expf(scores[e] - m) * values[c * FEAT + lane];
    }
    out[(long long)node * FEAT + lane] = acc * invs;
}

// ---------- main passes: column-phased gather (vq half is L2-resident) ----------
// PASS 0: edges with col <  csplit -> normalized fp16 partial into ws (plain store)
// PASS 1: edges with col >= csplit -> + partial -> out (nt store, host-consumed)
// 2 nodes per wave; lane = (q = lane>>4 quadrant, f4 = lane&15 dword slot).
template<int PASS>
__global__ __launch_bounds__(256) void gat_pass_kernel(
    const void* __restrict__ row_ptr_v,
    const void* __restrict__ col_idx_v,
    const float* __restrict__ scores,
    const int* __restrict__ vq,
    const float* __restrict__ scale,
    const float* __restrict__ values,
    _Float16* __restrict__ partial,
    float* __restrict__ out,
    int num_nodes, long long num_edges, int csplit)
{
    const int wv   = blockIdx.x * 4 + (threadIdx.x >> 6);
    const int lane = threadIdx.x & 63;
    const int wid0 = wv * 2;
    if (wid0 >= num_nodes) return;

    const int* rp32 = (const int*)row_ptr_v;
    const bool idx64 = (rp32[1] == 0);

    const int q  = lane >> 4;
    const int f4 = lane & 15;

    const long long base = (long long)wid0 * 16;
    const bool inb = (wid0 + 2 <= num_nodes) && (base + 32 <= num_edges);

    if (inb && !idx64) {
        const int b16 = wid0 * 16;
        const int r0 = rp32[wid0], r1 = rp32[wid0 + 1], r2 = rp32[wid0 + 2];

        const float* sb = scores + base;
        const int*   cb = (const int*)col_idx_v + base;
        f32x4 sv0 = __builtin_nontemporal_load((const f32x4*)sb + q);
        f32x4 sv1 = __builtin_nontemporal_load((const f32x4*)(sb + 16) + q);
        i32x4 cv0 = __builtin_nontemporal_load((const i32x4*)cb + q);
        i32x4 cv1 = __builtin_nontemporal_load((const i32x4*)(cb + 16) + q);

        // speculative early partial read (PASS 1 only); ignored on fallback
        f16x4 pp = (f16x4){(_Float16)0, (_Float16)0, (_Float16)0, (_Float16)0};
        if (PASS == 1) {
            if (q == 0)      pp = *((const f16x4*)(partial + ((long long)wid0 << 6)) + f4);
            else if (q == 1) pp = *((const f16x4*)(partial + ((long long)(wid0 + 1) << 6)) + f4);
        }

        // per-edge pass masks (16-lane-group uniform)
        const bool in00 = (PASS == 0) ? (cv0.x < csplit) : (cv0.x >= csplit);
        const bool in01 = (PASS == 0) ? (cv0.y < csplit) : (cv0.y >= csplit);
        const bool in02 = (PASS == 0) ? (cv0.z < csplit) : (cv0.z >= csplit);
        const bool in03 = (PASS == 0) ? (cv0.w < csplit) : (cv0.w >= csplit);
        const bool in10 = (PASS == 0) ? (cv1.x < csplit) : (cv1.x >= csplit);
        const bool in11 = (PASS == 0) ? (cv1.y < csplit) : (cv1.y >= csplit);
        const bool in12 = (PASS == 0) ? (cv1.z < csplit) : (cv1.z >= csplit);
        const bool in13 = (PASS == 0) ? (cv1.w < csplit) : (cv1.w >= csplit);

        // predicated row gathers — only this pass's half of vq is touched
        int p00 = 0, p01 = 0, p02 = 0, p03 = 0;
        int p10 = 0, p11 = 0, p12 = 0, p13 = 0;
        if (in00) p00 = vq[((unsigned)cv0.x << 4) + f4];
        if (in01) p01 = vq[((unsigned)cv0.y << 4) + f4];
        if (in02) p02 = vq[((unsigned)cv0.z << 4) + f4];
        if (in03) p03 = vq[((unsigned)cv0.w << 4) + f4];
        if (in10) p10 = vq[((unsigned)cv1.x << 4) + f4];
        if (in11) p11 = vq[((unsigned)cv1.y << 4) + f4];
        if (in12) p12 = vq[((unsigned)cv1.z << 4) + f4];
        if (in13) p13 = vq[((unsigned)cv1.w << 4) + f4];

        // scale array is 0.4MB -> L2-resident; load unpredicated
        float s00 = scale[cv0.x], s01 = scale[cv0.y];
        float s02 = scale[cv0.z], s03 = scale[cv0.w];
        float s10 = scale[cv1.x], s11 = scale[cv1.y];
        float s12 = scale[cv1.z], s13 = scale[cv1.w];

        const bool uni = (r0 == b16) && (r1 == b16 + 16) && (r2 == b16 + 32);
        if (uni) {
            // full softmax both passes (scores are re-streamed anyway)
            float m0 = fmaxf(fmaxf(sv0.x, sv0.y), fmaxf(sv0.z, sv0.w));
            m0 = fmaxf(m0, __shfl_xor(m0, 16));
            m0 = fmaxf(m0, __shfl_xor(m0, 32));
            float w00 = __expf(sv0.x - m0), w01 = __expf(sv0.y - m0);
            float w02 = __expf(sv0.z - m0), w03 = __expf(sv0.w - m0);
            float t0 = w00 + w01 + w02 + w03;
            t0 += __shfl_xor(t0, 16);
            t0 += __shfl_xor(t0, 32);
            const float inv0 = 1.0f / t0;

            float m1 = fmaxf(fmaxf(sv1.x, sv1.y), fmaxf(sv1.z, sv1.w));
            m1 = fmaxf(m1, __shfl_xor(m1, 16));
            m1 = fmaxf(m1, __shfl_xor(m1, 32));
            float w10 = __expf(sv1.x - m1), w11 = __expf(sv1.y - m1);
            float w12 = __expf(sv1.z - m1), w13 = __expf(sv1.w - m1);
            float t1 = w10 + w11 + w12 + w13;
            t1 += __shfl_xor(t1, 16);
            t1 += __shfl_xor(t1, 32);
            const float inv1 = 1.0f / t1;

            // masked effective weights (scale folded in)
            const float wk00 = in00 ? w00 * s00 : 0.0f;
            const float wk01 = in01 ? w01 * s01 : 0.0f;
            const float wk02 = in02 ? w02 * s02 : 0.0f;
            const float wk03 = in03 ? w03 * s03 : 0.0f;
            const float wk10 = in10 ? w10 * s10 : 0.0f;
            const float wk11 = in11 ? w11 * s11 : 0.0f;
            const float wk12 = in12 ? w12 * s12 : 0.0f;
            const float wk13 = in13 ? w13 * s13 : 0.0f;

            float B0 = wk00 + wk01 + wk02 + wk03;   // subset bias term
            float B1 = wk10 + wk11 + wk12 + wk13;

            f32x4 acc0 = {0,0,0,0}, acc1 = {0,0,0,0};
            dq_acc(p00, wk00, acc0); dq_acc(p01, wk01, acc0);
            dq_acc(p02, wk02, acc0); dq_acc(p03, wk03, acc0);
            dq_acc(p10, wk10, acc1); dq_acc(p11, wk11, acc1);
            dq_acc(p12, wk12, acc1); dq_acc(p13, wk13, acc1);

            B0 += __shfl_xor(B0, 16);  B0 += __shfl_xor(B0, 32);
            B1 += __shfl_xor(B1, 16);  B1 += __shfl_xor(B1, 32);
            acc0.x += __shfl_xor(acc0.x, 16);  acc0.x += __shfl_xor(acc0.x, 32);
            acc0.y += __shfl_xor(acc0.y, 16);  acc0.y += __shfl_xor(acc0.y, 32);
            acc0.z += __shfl_xor(acc0.z, 16);  acc0.z += __shfl_xor(acc0.z, 32);
            acc0.w += __shfl_xor(acc0.w, 16);  acc0.w += __shfl_xor(acc0.w, 32);
            acc1.x += __shfl_xor(acc1.x, 16);  acc1.x += __shfl_xor(acc1.x, 32);
            acc1.y += __shfl_xor(acc1.y, 16);  acc1.y += __shfl_xor(acc1.y, 32);
            acc1.z += __shfl_xor(acc1.z, 16);  acc1.z += __shfl_xor(acc1.z, 32);
            acc1.w += __shfl_xor(acc1.w, 16);  acc1.w += __shfl_xor(acc1.w, 32);

            const float b0 = 128.0f * B0, b1 = 128.0f * B1;
            f32x4 r0v, r1v;
            r0v.x = (acc0.x - b0) * inv0;  r0v.y = (acc0.y - b0) * inv0;
            r0v.z = (acc0.z - b0) * inv0;  r0v.w = (acc0.w - b0) * inv0;
            r1v.x = (acc1.x - b1) * inv1;  r1v.y = (acc1.y - b1) * inv1;
            r1v.z = (acc1.z - b1) * inv1;  r1v.w = (acc1.w - b1) * inv1;

            if (PASS == 0) {
                // normalized fp16 partial -> ws (plain store, device-consumed)
                if (q == 0) {
                    f16x4 h; h.x = (_Float16)r0v.x; h.y = (_Float16)r0v.y;
                             h.z = (_Float16)r0v.z; h.w = (_Float16)r0v.w;
                    *((f16x4*)(partial + ((long long)wid0 << 6)) + f4) = h;
                } else if (q == 1) {
                    f16x4 h; h.x = (_Float16)r1v.x; h.y = (_Float16)r1v.y;
                             h.z = (_Float16)r1v.z; h.w = (_Float16)r1v.w;
                    *((f16x4*)(partial + ((long long)(wid0 + 1) << 6)) + f4) = h;
                }
            } else {
                if (q == 0) {
                    r0v.x += (float)pp.x; r0v.y += (float)pp.y;
                    r0v.z += (float)pp.z; r0v.w += (float)pp.w;
                    __builtin_nontemporal_store(r0v,
                        (f32x4*)(out + ((long long)wid0 << 6)) + f4);
                } else if (q == 1) {
                    r1v.x += (float)pp.x; r1v.y += (float)pp.y;
                    r1v.z += (float)pp.z; r1v.w += (float)pp.w;
                    __builtin_nontemporal_store(r1v,
                        (f32x4*)(out + ((long long)(wid0 + 1) << 6)) + f4);
                }
            }
            return;
        }
    }

    // fallback: PASS 0 does nothing; PASS 1 computes the full node generically
    if (PASS == 1) {
        for (int n = 0; n < 2; ++n) {
            const int node = wid0 + n;
            if (node >= num_nodes) break;
            node_generic(row_ptr_v, col_idx_v, scores, values, out, node, lane, idx64);
        }
    }
}

// fp32-only variant (workspace too small)
__global__ __launch_bounds__(256) void gat_agg_fp32_kernel(
    const void* __restrict__ row_ptr_v, const void* __restrict__ col_idx_v,
    const float* __restrict__ scores, const float* __restrict__ values,
    float* __restrict__ out, int num_nodes)
{
    const int wid  = blockIdx.x * 4 + (threadIdx.x >> 6);
    const int lane = threadIdx.x & 63;
    if (wid >= num_nodes) return;
    const int* rp32 = (const int*)row_ptr_v;
    const bool idx64 = (rp32[1] == 0);
    node_generic(row_ptr_v, col_idx_v, scores, values, out, wid, lane, idx64);
}

extern "C" void kernel_launch(void* const* d_in, const int* in_sizes, int n_in,
                              void* d_out, int out_size, void* d_ws, size_t ws_size,
                              hipStream_t stream) {
    const void*  row_ptr = d_in[0];
    const void*  col_idx = d_in[1];
    const float* scores  = (const float*)d_in[2];
    const float* values  = (const float*)d_in[3];
    float*       out     = (float*)d_out;

    const int num_nodes = in_sizes[0] - 1;          // 100000
    const long long num_edges = (long long)in_sizes[2];
    const long long nvals = (long long)in_sizes[3]; // rows * 64
    const int num_rows = (int)(nvals / FEAT);

    const size_t scale_off   = ((size_t)nvals + 511) & ~(size_t)511;   // u8 vq
    const size_t partial_off = (scale_off + (size_t)num_rows * sizeof(float) + 511)
                               & ~(size_t)511;
    const size_t need = partial_off + (size_t)nvals * sizeof(_Float16);

    if (ws_size >= need) {
        int*      vq      = (int*)d_ws;
        float*    scale   = (float*)((char*)d_ws + scale_off);
        _Float16* partial = (_Float16*)((char*)d_ws + partial_off);

        const int qblocks = (num_rows + 63) / 64;   // 64 rows per block
        hipLaunchKernelGGL(quant_kernel, dim3(qblocks), dim3(256), 0, stream,
                           values, vq, scale, num_rows);

        const int csplit = num_rows >> 1;
        const int nodes_per_block = 4 * 2;          // 4 waves x 2 nodes
        const int blocks = (num_nodes + nodes_per_block - 1) / nodes_per_block;
        hipLaunchKernelGGL((gat_pass_kernel<0>), dim3(blocks), dim3(256), 0, stream,
                           row_ptr, col_idx, scores, vq, scale, values, partial, out,
                           num_nodes, num_edges, csplit);
        hipLaunchKernelGGL((gat_pass_kernel<1>), dim3(blocks), dim3(256), 0, stream,
                           row_ptr, col_idx, scores, vq, scale, values, partial, out,
                           num_nodes, num_edges, csplit);
    } else {
        const int blocks = (num_nodes + 3) / 4;
        hipLaunchKernelGGL(gat_agg_fp32_kernel, dim3(blocks), dim3(256), 0, stream,
                           row_ptr, col_idx, scores, values, out, num_nodes);
    }
}